// Round 8
// baseline (254.334 us; speedup 1.0000x reference)
//
#include <hip/hip_runtime.h>
#include <hip/hip_bf16.h>

#define B_  16384
#define I_  512
#define H1_ 256
#define H2_ 128
#define E_  8
#define T_  2

typedef __attribute__((ext_vector_type(8))) short short8;
typedef __attribute__((ext_vector_type(4))) float float4_t;

__device__ inline unsigned short f2bf(float f) {
    union { float f; unsigned u; } v; v.f = f;
    unsigned r = v.u + 0x7FFFu + ((v.u >> 16) & 1u);
    return (unsigned short)(r >> 16);
}

// async global->LDS, 16B per lane. LDS dest = wave-uniform base + lane*16.
__device__ inline void async_copy16(const unsigned short* g, unsigned short* l) {
    __builtin_amdgcn_global_load_lds(
        (const __attribute__((address_space(1))) void*)g,
        (__attribute__((address_space(3))) void*)l,
        16, 0, 0);
}

// ================= prep + gates megakernel (one dispatch) =================
__global__ void prep_gates_kernel(const float* __restrict__ x,
                                  unsigned short* __restrict__ xb,
                                  const float* __restrict__ W1,
                                  unsigned short* __restrict__ w1t,
                                  const float* __restrict__ W2,
                                  unsigned short* __restrict__ w2t,
                                  const float* __restrict__ Wg,
                                  const float* __restrict__ bg,
                                  float* __restrict__ gates) {
    __shared__ __align__(16) char smem[16 * 520 * 2 + 4 * 16 * 16 * 4];  // 20.6 KB
    int bid = blockIdx.x;
    int t = threadIdx.x;

    if (bid < 1024) {
        unsigned short* wgtL = (unsigned short*)smem;          // [16][520] padded
        float (*red)[16][16] = (float (*)[16][16])(smem + 16 * 520 * 2);
#pragma unroll
        for (int j = 0; j < 32; ++j) {
            int idx = j * 256 + t;               // 0..8191
            int e = idx & 7, i = (idx >> 3) & 511, task = idx >> 12;
            wgtL[(task * 8 + e) * 520 + i] = f2bf(Wg[idx]);
        }
        __syncthreads();

        int w = t >> 6, lane = t & 63;
        int col = lane & 15, quad = lane >> 4;
        int b0 = bid * 16;
        int k0 = w * 128;
        const float* xr = x + (size_t)(b0 + col) * I_ + k0 + quad * 8;
        unsigned short* xw = xb + (size_t)(b0 + col) * I_ + k0 + quad * 8;
        const unsigned short* bL = &wgtL[col * 520 + k0 + quad * 8];
        float4_t acc = {0.f, 0.f, 0.f, 0.f};
#pragma unroll
        for (int ks = 0; ks < 128; ks += 32) {
            float4_t xa = *(const float4_t*)(xr + ks);
            float4_t xc = *(const float4_t*)(xr + ks + 4);
            short8 a;
            a[0] = (short)f2bf(xa[0]); a[1] = (short)f2bf(xa[1]);
            a[2] = (short)f2bf(xa[2]); a[3] = (short)f2bf(xa[3]);
            a[4] = (short)f2bf(xc[0]); a[5] = (short)f2bf(xc[1]);
            a[6] = (short)f2bf(xc[2]); a[7] = (short)f2bf(xc[3]);
            *(short8*)(xw + ks) = a;
            short8 b = *(const short8*)(bL + ks);
            acc = __builtin_amdgcn_mfma_f32_16x16x32_bf16(a, b, acc, 0, 0, 0);
        }
#pragma unroll
        for (int p = 0; p < 4; ++p)
            red[w][quad * 4 + p][col] = acc[p];
        __syncthreads();
        int r = t >> 4, te = t & 15;
        float v = red[0][r][te] + red[1][r][te] + red[2][r][te] + red[3][r][te] + bg[te];
        float m = v;
        m = fmaxf(m, __shfl_xor(m, 1));
        m = fmaxf(m, __shfl_xor(m, 2));
        m = fmaxf(m, __shfl_xor(m, 4));
        float ev = __expf(v - m);
        float s = ev;
        s += __shfl_xor(s, 1);
        s += __shfl_xor(s, 2);
        s += __shfl_xor(s, 4);
        gates[(size_t)te * B_ + b0 + r] = ev / s;
    } else {
        float (*tile)[33] = (float (*)[33])smem;
        const float* in; unsigned short* outp; int R, C, e, r0, c0;
        if (bid < 2048) {
            int tl = bid - 1024;               // 8 e x 16 rblk x 8 cblk
            e = tl >> 7; int rem = tl & 127;
            R = I_; C = H1_;
            r0 = (rem >> 3) * 32; c0 = (rem & 7) * 32;
            in = W1; outp = w1t;
        } else {
            int tl = bid - 2048;               // 8 e x 8 rblk x 4 cblk
            e = tl >> 5; int rem = tl & 31;
            R = H1_; C = H2_;
            r0 = (rem >> 2) * 32; c0 = (rem & 3) * 32;
            in = W2; outp = w2t;
        }
        const float* inp = in + (size_t)e * R * C;
        unsigned short* op = outp + (size_t)e * R * C;
        int tx = t & 31, ty = t >> 5;          // (32, 8)
#pragma unroll
        for (int j = 0; j < 32; j += 8)
            tile[ty + j][tx] = inp[(size_t)(r0 + ty + j) * C + c0 + tx];
        __syncthreads();
#pragma unroll
        for (int j = 0; j < 32; j += 8)
            op[(size_t)(c0 + ty + j) * R + r0 + tx] = f2bf(tile[tx][ty + j]);
    }
}

// ---------------- layer 1 grouped GEMM: h[e] = relu(xb * w1t[e]^T + b1[e]) bf16 ----------------
__global__ void gemm_relu_kernel(const unsigned short* __restrict__ A, size_t aSE,
                                 const unsigned short* __restrict__ Bt, size_t bSE,
                                 const float* __restrict__ bias, int biasSE,
                                 unsigned short* __restrict__ C, size_t cSE,
                                 int K, int lda, int ldb, int ldc) {
    __shared__ unsigned short smem[128 * 136];   // 34 KB: As|Bs, aliased by padded C-tile
    unsigned short* As = smem;                    // 128*64
    unsigned short* Bs = smem + 128 * 64;         // 128*64
    int e = blockIdx.z;
    const unsigned short* Ae = A + (size_t)e * aSE;
    const unsigned short* Be = Bt + (size_t)e * bSE;
    const float* biasE = bias + (size_t)e * biasSE;
    unsigned short* Ce = C + (size_t)e * cSE;
    int m0 = blockIdx.x * 128, n0 = blockIdx.y * 128;
    int t = threadIdx.x, w = t >> 6, lane = t & 63;
    int col = lane & 15, quad = lane >> 4;
    int wm = (w & 1) * 64, wn = (w >> 1) * 64;

    float4_t acc[4][4];
#pragma unroll
    for (int mi = 0; mi < 4; ++mi)
#pragma unroll
        for (int ni = 0; ni < 4; ++ni)
            acc[mi][ni] = (float4_t){0.f, 0.f, 0.f, 0.f};

    int rT = t >> 3;
    int gk = (((t & 7) ^ (rT & 7))) * 8;
    const unsigned short* aG = Ae + (size_t)(m0 + rT) * lda + gk;
    const unsigned short* bG = Be + (size_t)(n0 + rT) * ldb + gk;
    unsigned short* aL = As + (size_t)w * 64 * 8;
    unsigned short* bL = Bs + (size_t)w * 64 * 8;

    for (int k0 = 0; k0 < K; k0 += 64) {
#pragma unroll
        for (int j = 0; j < 4; ++j) {
            async_copy16(aG + (size_t)j * 32 * lda + k0, aL + j * 2048);
            async_copy16(bG + (size_t)j * 32 * ldb + k0, bL + j * 2048);
        }
        __syncthreads();
#pragma unroll
        for (int kk = 0; kk < 64; kk += 32) {
            int q = (kk >> 3) + quad;
            short8 af[4], bf[4];
#pragma unroll
            for (int mi = 0; mi < 4; ++mi) {
                int r = wm + mi * 16 + col;
                af[mi] = *(const short8*)&As[r * 64 + ((q ^ (r & 7)) * 8)];
            }
#pragma unroll
            for (int ni = 0; ni < 4; ++ni) {
                int r = wn + ni * 16 + col;
                bf[ni] = *(const short8*)&Bs[r * 64 + ((q ^ (r & 7)) * 8)];
            }
#pragma unroll
            for (int mi = 0; mi < 4; ++mi)
#pragma unroll
                for (int ni = 0; ni < 4; ++ni)
                    acc[mi][ni] = __builtin_amdgcn_mfma_f32_16x16x32_bf16(af[mi], bf[ni], acc[mi][ni], 0, 0, 0);
        }
        __syncthreads();
    }
    // after final barrier all LDS reads are done -> safe to alias as padded C-tile
    unsigned short* Ct = smem;   // 128 rows x stride 136
#pragma unroll
    for (int ni = 0; ni < 4; ++ni) {
        int c = wn + ni * 16 + col;
        float bv = biasE[n0 + c];
#pragma unroll
        for (int mi = 0; mi < 4; ++mi) {
            int rbase = wm + mi * 16 + quad * 4;
#pragma unroll
            for (int p = 0; p < 4; ++p) {
                float v = acc[mi][ni][p] + bv;
                v = v > 0.f ? v : 0.f;
                Ct[(rbase + p) * 136 + c] = f2bf(v);
            }
        }
    }
    __syncthreads();
    int rr = t >> 4, sl = t & 15;
#pragma unroll
    for (int pass = 0; pass < 8; ++pass) {
        int row = pass * 16 + rr;
        short8 vv = *(const short8*)&Ct[row * 136 + sl * 8];
        *(short8*)&Ce[(size_t)(m0 + row) * ldc + n0 + sl * 8] = vv;
    }
}

// ---------------- layer2 + gated combine: atomic-epilogue GEMM ----------------
// Grid (B/128, E) = 1024 blocks (~4-5 blocks/CU -- the occupancy regime where
// this GEMM structure is proven). Per block: 128x128xK=256 MFMA GEMM for one
// expert; epilogue does bias+relu, scales by the two task gates (LDS-staged),
// and atomicAdds into out[T][B][H2]. No eo materialization; W2t staged once
// per block. Requires out pre-zeroed (hipMemsetAsync in kernel_launch).
__global__ void gemm2_combine_kernel(const unsigned short* __restrict__ h,
                                     const unsigned short* __restrict__ w2t,
                                     const float* __restrict__ b2,
                                     const float* __restrict__ gates,
                                     float* __restrict__ out) {
    __shared__ unsigned short smem[128 * 128];    // 32 KB: As | Bs
    __shared__ float gL[2][128];                  // 1 KB: task gates for 128 rows
    unsigned short* As = smem;                    // 128*64
    unsigned short* Bs = smem + 128 * 64;         // 128*64
    int e = blockIdx.y;
    int m0 = blockIdx.x * 128;
    const unsigned short* Ae = h + (size_t)e * B_ * H1_;
    const unsigned short* Be = w2t + (size_t)e * H2_ * H1_;
    int t = threadIdx.x, w = t >> 6, lane = t & 63;
    int col = lane & 15, quad = lane >> 4;
    int wm = (w & 1) * 64, wn = (w >> 1) * 64;

    {   // stage gates: task = t>>7, local row = t&127
        int task = t >> 7, r = t & 127;
        gL[task][r] = gates[(size_t)(task * 8 + e) * B_ + m0 + r];
    }   // first read is after the k-loop's __syncthreads

    float4_t acc[4][4];
#pragma unroll
    for (int mi = 0; mi < 4; ++mi)
#pragma unroll
        for (int ni = 0; ni < 4; ++ni)
            acc[mi][ni] = (float4_t){0.f, 0.f, 0.f, 0.f};

    int rT = t >> 3;
    int gk = (((t & 7) ^ (rT & 7))) * 8;
    const unsigned short* aG = Ae + (size_t)(m0 + rT) * H1_ + gk;
    const unsigned short* bG = Be + (size_t)rT * H1_ + gk;
    unsigned short* aL = As + (size_t)w * 64 * 8;
    unsigned short* bL = Bs + (size_t)w * 64 * 8;

    for (int k0 = 0; k0 < H1_; k0 += 64) {
#pragma unroll
        for (int j = 0; j < 4; ++j) {
            async_copy16(aG + (size_t)j * 32 * H1_ + k0, aL + j * 2048);
            async_copy16(bG + (size_t)j * 32 * H1_ + k0, bL + j * 2048);
        }
        __syncthreads();
#pragma unroll
        for (int kk = 0; kk < 64; kk += 32) {
            int q = (kk >> 3) + quad;
            short8 af[4], bf[4];
#pragma unroll
            for (int mi = 0; mi < 4; ++mi) {
                int r = wm + mi * 16 + col;
                af[mi] = *(const short8*)&As[r * 64 + ((q ^ (r & 7)) * 8)];
            }
#pragma unroll
            for (int ni = 0; ni < 4; ++ni) {
                int r = wn + ni * 16 + col;
                bf[ni] = *(const short8*)&Bs[r * 64 + ((q ^ (r & 7)) * 8)];
            }
#pragma unroll
            for (int mi = 0; mi < 4; ++mi)
#pragma unroll
                for (int ni = 0; ni < 4; ++ni)
                    acc[mi][ni] = __builtin_amdgcn_mfma_f32_16x16x32_bf16(af[mi], bf[ni], acc[mi][ni], 0, 0, 0);
        }
        __syncthreads();
    }

    // epilogue: bias + relu + gated atomic accumulate into out[T][B][H2]
    float* out1 = out + (size_t)B_ * H2_;
#pragma unroll
    for (int ni = 0; ni < 4; ++ni) {
        int c = wn + ni * 16 + col;
        float bv = b2[e * H2_ + c];
#pragma unroll
        for (int mi = 0; mi < 4; ++mi) {
            int rbase = wm + mi * 16 + quad * 4;
#pragma unroll
            for (int p = 0; p < 4; ++p) {
                int rl = rbase + p;
                float v = acc[mi][ni][p] + bv;
                v = v > 0.f ? v : 0.f;
                size_t off = (size_t)(m0 + rl) * H2_ + c;
                atomicAdd(&out[off], gL[0][rl] * v);
                atomicAdd(&out1[off], gL[1][rl] * v);
            }
        }
    }
}

extern "C" void kernel_launch(void* const* d_in, const int* in_sizes, int n_in,
                              void* d_out, int out_size, void* d_ws, size_t ws_size,
                              hipStream_t stream) {
    const float* x  = (const float*)d_in[0];
    const float* W1 = (const float*)d_in[1];
    const float* b1 = (const float*)d_in[2];
    const float* W2 = (const float*)d_in[3];
    const float* b2 = (const float*)d_in[4];
    const float* Wg = (const float*)d_in[5];
    const float* bg = (const float*)d_in[6];
    float* out = (float*)d_out;

    char* ws = (char*)d_ws;
    unsigned short* xb    = (unsigned short*)(ws);                // 16,777,216 B
    unsigned short* w1t   = (unsigned short*)(ws + 16777216);     //  2,097,152 B
    unsigned short* w2t   = (unsigned short*)(ws + 18874368);     //    524,288 B
    float*          gates = (float*)(ws + 19398656);              //  1,048,576 B  [16][B]
    unsigned short* h     = (unsigned short*)(ws + 20447232);     // 67,108,864 B
    // total: 87,556,096 B

    // zero out (atomic accumulation target); graph-capturable async memset
    hipMemsetAsync(out, 0, (size_t)out_size * sizeof(float), stream);

    // dispatch 1: all prep + gates (x->bf16, W1^T, W2^T, gate softmax)
    prep_gates_kernel<<<dim3(2304), 256, 0, stream>>>(x, xb, W1, w1t, W2, w2t, Wg, bg, gates);

    // dispatch 2: layer 1: h[e] = relu(xb * w1t[e]^T + b1[e])   M=B, N=H1, K=I
    gemm_relu_kernel<<<dim3(B_ / 128, H1_ / 128, E_), 256, 0, stream>>>(
        xb, 0, w1t, (size_t)H1_ * I_, b1, H1_, h, (size_t)B_ * H1_, I_, I_, I_, H1_);

    // dispatch 3: layer 2 + gated combine (atomic epilogue)
    gemm2_combine_kernel<<<dim3(B_ / 128, E_), 256, 0, stream>>>(h, w2t, b2, gates, out);
}

// Round 9
// 157.356 us; speedup vs baseline: 1.6163x; 1.6163x over previous
//
#include <hip/hip_runtime.h>
#include <hip/hip_bf16.h>

#define B_  16384
#define I_  512
#define H1_ 256
#define H2_ 128
#define E_  8
#define T_  2

typedef __attribute__((ext_vector_type(8))) short short8;
typedef __attribute__((ext_vector_type(4))) float float4_t;

__device__ inline unsigned short f2bf(float f) {
    union { float f; unsigned u; } v; v.f = f;
    unsigned r = v.u + 0x7FFFu + ((v.u >> 16) & 1u);
    return (unsigned short)(r >> 16);
}

// async global->LDS, 16B per lane. LDS dest = wave-uniform base + lane*16.
__device__ inline void async_copy16(const unsigned short* g, unsigned short* l) {
    __builtin_amdgcn_global_load_lds(
        (const __attribute__((address_space(1))) void*)g,
        (__attribute__((address_space(3))) void*)l,
        16, 0, 0);
}

// ================= prep + gates megakernel (one dispatch) =================
__global__ void prep_gates_kernel(const float* __restrict__ x,
                                  unsigned short* __restrict__ xb,
                                  const float* __restrict__ W1,
                                  unsigned short* __restrict__ w1t,
                                  const float* __restrict__ W2,
                                  unsigned short* __restrict__ w2t,
                                  const float* __restrict__ Wg,
                                  const float* __restrict__ bg,
                                  float* __restrict__ gates) {
    __shared__ __align__(16) char smem[16 * 520 * 2 + 4 * 16 * 16 * 4];  // 20.6 KB
    int bid = blockIdx.x;
    int t = threadIdx.x;

    if (bid < 1024) {
        unsigned short* wgtL = (unsigned short*)smem;          // [16][520] padded
        float (*red)[16][16] = (float (*)[16][16])(smem + 16 * 520 * 2);
#pragma unroll
        for (int j = 0; j < 32; ++j) {
            int idx = j * 256 + t;               // 0..8191
            int e = idx & 7, i = (idx >> 3) & 511, task = idx >> 12;
            wgtL[(task * 8 + e) * 520 + i] = f2bf(Wg[idx]);
        }
        __syncthreads();

        int w = t >> 6, lane = t & 63;
        int col = lane & 15, quad = lane >> 4;
        int b0 = bid * 16;
        int k0 = w * 128;
        const float* xr = x + (size_t)(b0 + col) * I_ + k0 + quad * 8;
        unsigned short* xw = xb + (size_t)(b0 + col) * I_ + k0 + quad * 8;
        const unsigned short* bL = &wgtL[col * 520 + k0 + quad * 8];
        float4_t acc = {0.f, 0.f, 0.f, 0.f};
#pragma unroll
        for (int ks = 0; ks < 128; ks += 32) {
            float4_t xa = *(const float4_t*)(xr + ks);
            float4_t xc = *(const float4_t*)(xr + ks + 4);
            short8 a;
            a[0] = (short)f2bf(xa[0]); a[1] = (short)f2bf(xa[1]);
            a[2] = (short)f2bf(xa[2]); a[3] = (short)f2bf(xa[3]);
            a[4] = (short)f2bf(xc[0]); a[5] = (short)f2bf(xc[1]);
            a[6] = (short)f2bf(xc[2]); a[7] = (short)f2bf(xc[3]);
            *(short8*)(xw + ks) = a;
            short8 b = *(const short8*)(bL + ks);
            acc = __builtin_amdgcn_mfma_f32_16x16x32_bf16(a, b, acc, 0, 0, 0);
        }
#pragma unroll
        for (int p = 0; p < 4; ++p)
            red[w][quad * 4 + p][col] = acc[p];
        __syncthreads();
        int r = t >> 4, te = t & 15;
        float v = red[0][r][te] + red[1][r][te] + red[2][r][te] + red[3][r][te] + bg[te];
        float m = v;
        m = fmaxf(m, __shfl_xor(m, 1));
        m = fmaxf(m, __shfl_xor(m, 2));
        m = fmaxf(m, __shfl_xor(m, 4));
        float ev = __expf(v - m);
        float s = ev;
        s += __shfl_xor(s, 1);
        s += __shfl_xor(s, 2);
        s += __shfl_xor(s, 4);
        gates[(size_t)te * B_ + b0 + r] = ev / s;
    } else {
        float (*tile)[33] = (float (*)[33])smem;
        const float* in; unsigned short* outp; int R, C, e, r0, c0;
        if (bid < 2048) {
            int tl = bid - 1024;               // 8 e x 16 rblk x 8 cblk
            e = tl >> 7; int rem = tl & 127;
            R = I_; C = H1_;
            r0 = (rem >> 3) * 32; c0 = (rem & 7) * 32;
            in = W1; outp = w1t;
        } else {
            int tl = bid - 2048;               // 8 e x 8 rblk x 4 cblk
            e = tl >> 5; int rem = tl & 31;
            R = H1_; C = H2_;
            r0 = (rem >> 2) * 32; c0 = (rem & 3) * 32;
            in = W2; outp = w2t;
        }
        const float* inp = in + (size_t)e * R * C;
        unsigned short* op = outp + (size_t)e * R * C;
        int tx = t & 31, ty = t >> 5;          // (32, 8)
#pragma unroll
        for (int j = 0; j < 32; j += 8)
            tile[ty + j][tx] = inp[(size_t)(r0 + ty + j) * C + c0 + tx];
        __syncthreads();
#pragma unroll
        for (int j = 0; j < 32; j += 8)
            op[(size_t)(c0 + ty + j) * R + r0 + tx] = f2bf(tile[tx][ty + j]);
    }
}

// ---------------- layer 1 grouped GEMM: h[e] = relu(xb * w1t[e]^T + b1[e]) bf16 ----------------
__global__ void gemm_relu_kernel(const unsigned short* __restrict__ A, size_t aSE,
                                 const unsigned short* __restrict__ Bt, size_t bSE,
                                 const float* __restrict__ bias, int biasSE,
                                 unsigned short* __restrict__ C, size_t cSE,
                                 int K, int lda, int ldb, int ldc) {
    __shared__ unsigned short smem[128 * 136];   // 34 KB: As|Bs, aliased by padded C-tile
    unsigned short* As = smem;                    // 128*64
    unsigned short* Bs = smem + 128 * 64;         // 128*64
    int e = blockIdx.z;
    const unsigned short* Ae = A + (size_t)e * aSE;
    const unsigned short* Be = Bt + (size_t)e * bSE;
    const float* biasE = bias + (size_t)e * biasSE;
    unsigned short* Ce = C + (size_t)e * cSE;
    int m0 = blockIdx.x * 128, n0 = blockIdx.y * 128;
    int t = threadIdx.x, w = t >> 6, lane = t & 63;
    int col = lane & 15, quad = lane >> 4;
    int wm = (w & 1) * 64, wn = (w >> 1) * 64;

    float4_t acc[4][4];
#pragma unroll
    for (int mi = 0; mi < 4; ++mi)
#pragma unroll
        for (int ni = 0; ni < 4; ++ni)
            acc[mi][ni] = (float4_t){0.f, 0.f, 0.f, 0.f};

    int rT = t >> 3;
    int gk = (((t & 7) ^ (rT & 7))) * 8;
    const unsigned short* aG = Ae + (size_t)(m0 + rT) * lda + gk;
    const unsigned short* bG = Be + (size_t)(n0 + rT) * ldb + gk;
    unsigned short* aL = As + (size_t)w * 64 * 8;
    unsigned short* bL = Bs + (size_t)w * 64 * 8;

    for (int k0 = 0; k0 < K; k0 += 64) {
#pragma unroll
        for (int j = 0; j < 4; ++j) {
            async_copy16(aG + (size_t)j * 32 * lda + k0, aL + j * 2048);
            async_copy16(bG + (size_t)j * 32 * ldb + k0, bL + j * 2048);
        }
        __syncthreads();
#pragma unroll
        for (int kk = 0; kk < 64; kk += 32) {
            int q = (kk >> 3) + quad;
            short8 af[4], bf[4];
#pragma unroll
            for (int mi = 0; mi < 4; ++mi) {
                int r = wm + mi * 16 + col;
                af[mi] = *(const short8*)&As[r * 64 + ((q ^ (r & 7)) * 8)];
            }
#pragma unroll
            for (int ni = 0; ni < 4; ++ni) {
                int r = wn + ni * 16 + col;
                bf[ni] = *(const short8*)&Bs[r * 64 + ((q ^ (r & 7)) * 8)];
            }
#pragma unroll
            for (int mi = 0; mi < 4; ++mi)
#pragma unroll
                for (int ni = 0; ni < 4; ++ni)
                    acc[mi][ni] = __builtin_amdgcn_mfma_f32_16x16x32_bf16(af[mi], bf[ni], acc[mi][ni], 0, 0, 0);
        }
        __syncthreads();
    }
    // after final barrier all LDS reads are done -> safe to alias as padded C-tile
    unsigned short* Ct = smem;   // 128 rows x stride 136
#pragma unroll
    for (int ni = 0; ni < 4; ++ni) {
        int c = wn + ni * 16 + col;
        float bv = biasE[n0 + c];
#pragma unroll
        for (int mi = 0; mi < 4; ++mi) {
            int rbase = wm + mi * 16 + quad * 4;
#pragma unroll
            for (int p = 0; p < 4; ++p) {
                float v = acc[mi][ni][p] + bv;
                v = v > 0.f ? v : 0.f;
                Ct[(rbase + p) * 136 + c] = f2bf(v);
            }
        }
    }
    __syncthreads();
    int rr = t >> 4, sl = t & 15;
#pragma unroll
    for (int pass = 0; pass < 8; ++pass) {
        int row = pass * 16 + rr;
        short8 vv = *(const short8*)&Ct[row * 136 + sl * 8];
        *(short8*)&Ce[(size_t)(m0 + row) * ldc + n0 + sl * 8] = vv;
    }
}

// ---------------- fused layer2 + gated combine, in-block expert reduction ----------------
// Tile 64 rows x 64 cols, grid (B/64, 2) = 512 blocks -> 2 blocks/CU (68 KB LDS),
// 8 waves/CU for cross-block barrier overlap. Per expert: stage FULL K=256
// (h 32 KB + W2half 32 KB, one barrier pair), 32 MFMA/wave, accumulate gated
// towers in registers. Plain coalesced stores; no atomics, no eo buffer.
// W2 restage total: 0.5MB*256 = 128 MB; h: 2x67 = 134 MB; ~262 MB LDS staging.
__global__ void fused_l2_combine_kernel(const unsigned short* __restrict__ h,
                                        const unsigned short* __restrict__ w2t,
                                        const float* __restrict__ b2,
                                        const float* __restrict__ gates,
                                        float* __restrict__ out) {
    __shared__ unsigned short As[64 * 256];   // 32 KB: h slab (64 rows x K=256)
    __shared__ unsigned short Bs[64 * 256];   // 32 KB: W2t half (64 n x K=256)
    __shared__ float gL[16][64];              //  4 KB: gates [te][64 rows]

    int b0 = blockIdx.x * 64;
    int nh = blockIdx.y * 64;
    int t = threadIdx.x, w = t >> 6, lane = t & 63;
    int col = lane & 15, quad = lane >> 4;
    int wm = (w & 1) * 32, wn = (w >> 1) * 32;

    {   // stage gates (first read after e=0's barriers)
        int te = t >> 4, r4 = (t & 15) * 4;
        *(float4_t*)&gL[te][r4] = *(const float4_t*)&gates[(size_t)te * B_ + b0 + r4];
    }

    float4_t tw0[2][2], tw1[2][2];
#pragma unroll
    for (int mi = 0; mi < 2; ++mi)
#pragma unroll
        for (int ni = 0; ni < 2; ++ni) {
            tw0[mi][ni] = (float4_t){0.f, 0.f, 0.f, 0.f};
            tw1[mi][ni] = (float4_t){0.f, 0.f, 0.f, 0.f};
        }

    // staging geometry: issue j covers rows j*8..j*8+7 (4096 B); wave w writes
    // 1024 B at j*4096 + w*1024; lane's LDS chunk = lane&31 of row rL.
    int rL = w * 2 + (lane >> 5);       // row offset within 8-row issue group
    int cL = lane & 31;                  // lds 16B-chunk index within row

    for (int e = 0; e < E_; ++e) {
        const unsigned short* hE = h + ((size_t)e * B_ + b0) * H1_;
        const unsigned short* w2E = w2t + ((size_t)e * H2_ + nh) * H1_;

#pragma unroll
        for (int j = 0; j < 8; ++j) {
            int r = j * 8 + rL;
            int cg = (cL & 24) | ((cL ^ r) & 7);     // inverse of reader swizzle
            async_copy16(hE + (size_t)r * H1_ + cg * 8, As + j * 2048 + w * 512);
            async_copy16(w2E + (size_t)r * H1_ + cg * 8, Bs + j * 2048 + w * 512);
        }
        __syncthreads();

        float4_t acc[2][2];
#pragma unroll
        for (int mi = 0; mi < 2; ++mi)
#pragma unroll
            for (int ni = 0; ni < 2; ++ni)
                acc[mi][ni] = (float4_t){0.f, 0.f, 0.f, 0.f};

#pragma unroll
        for (int kk = 0; kk < 8; ++kk) {
            int c = kk * 4 + quad;                   // 16B-chunk index in K
            short8 af[2], bf[2];
#pragma unroll
            for (int mi = 0; mi < 2; ++mi) {
                int r = wm + mi * 16 + col;
                int l = (c & 24) | ((c ^ r) & 7);
                af[mi] = *(const short8*)&As[r * 256 + l * 8];
            }
#pragma unroll
            for (int ni = 0; ni < 2; ++ni) {
                int r = wn + ni * 16 + col;
                int l = (c & 24) | ((c ^ r) & 7);
                bf[ni] = *(const short8*)&Bs[r * 256 + l * 8];
            }
#pragma unroll
            for (int mi = 0; mi < 2; ++mi)
#pragma unroll
                for (int ni = 0; ni < 2; ++ni)
                    acc[mi][ni] = __builtin_amdgcn_mfma_f32_16x16x32_bf16(af[mi], bf[ni], acc[mi][ni], 0, 0, 0);
        }
        __syncthreads();

        // bias + relu + gated accumulate
#pragma unroll
        for (int ni = 0; ni < 2; ++ni) {
            float bv = b2[e * H2_ + nh + wn + ni * 16 + col];
#pragma unroll
            for (int mi = 0; mi < 2; ++mi) {
#pragma unroll
                for (int p = 0; p < 4; ++p) {
                    int rloc = wm + mi * 16 + quad * 4 + p;
                    float v = acc[mi][ni][p] + bv;
                    v = v > 0.f ? v : 0.f;
                    tw0[mi][ni][p] += gL[e][rloc] * v;
                    tw1[mi][ni][p] += gL[8 + e][rloc] * v;
                }
            }
        }
    }

    // write out [T][B][H2]
#pragma unroll
    for (int mi = 0; mi < 2; ++mi) {
#pragma unroll
        for (int ni = 0; ni < 2; ++ni) {
            int n = nh + wn + ni * 16 + col;
#pragma unroll
            for (int p = 0; p < 4; ++p) {
                int r = b0 + wm + mi * 16 + quad * 4 + p;
                out[(size_t)r * H2_ + n] = tw0[mi][ni][p];
                out[(size_t)B_ * H2_ + (size_t)r * H2_ + n] = tw1[mi][ni][p];
            }
        }
    }
}

extern "C" void kernel_launch(void* const* d_in, const int* in_sizes, int n_in,
                              void* d_out, int out_size, void* d_ws, size_t ws_size,
                              hipStream_t stream) {
    const float* x  = (const float*)d_in[0];
    const float* W1 = (const float*)d_in[1];
    const float* b1 = (const float*)d_in[2];
    const float* W2 = (const float*)d_in[3];
    const float* b2 = (const float*)d_in[4];
    const float* Wg = (const float*)d_in[5];
    const float* bg = (const float*)d_in[6];
    float* out = (float*)d_out;

    char* ws = (char*)d_ws;
    unsigned short* xb    = (unsigned short*)(ws);                // 16,777,216 B
    unsigned short* w1t   = (unsigned short*)(ws + 16777216);     //  2,097,152 B
    unsigned short* w2t   = (unsigned short*)(ws + 18874368);     //    524,288 B
    float*          gates = (float*)(ws + 19398656);              //  1,048,576 B  [16][B]
    unsigned short* h     = (unsigned short*)(ws + 20447232);     // 67,108,864 B
    // total: 87,556,096 B

    // dispatch 1: all prep + gates (x->bf16, W1^T, W2^T, gate softmax)
    prep_gates_kernel<<<dim3(2304), 256, 0, stream>>>(x, xb, W1, w1t, W2, w2t, Wg, bg, gates);

    // dispatch 2: layer 1: h[e] = relu(xb * w1t[e]^T + b1[e])   M=B, N=H1, K=I
    gemm_relu_kernel<<<dim3(B_ / 128, H1_ / 128, E_), 256, 0, stream>>>(
        xb, 0, w1t, (size_t)H1_ * I_, b1, H1_, h, (size_t)B_ * H1_, I_, I_, I_, H1_);

    // dispatch 3: fused layer 2 + gated combine (in-block expert reduction)
    fused_l2_combine_kernel<<<dim3(B_ / 64, 2), 256, 0, stream>>>(h, w2t, b2, gates, out);
}